// Round 4
// baseline (502.403 us; speedup 1.0000x reference)
//
#include <hip/hip_runtime.h>
#include <math.h>

// NeighborlistVerletNsq: N=4096 particles, P = N(N-1)/2 pairs.
// Outputs (flattened float32, in return order):
//   [0   , 4P ) pairs  [2,2P]: row0 = concat(i,j), row1 = concat(j,i)
//   [4P  , 6P ) d_full [2P,1]: concat(d_m, d_m)
//   [6P  , 12P) r_full [2P,3]: concat(r_m, -r_m), row-major
//   [12P , 14P) mask   [2P]  : concat(mask, mask) as 0/1
//
// R9: exploit sparsity. Only ~5.2e-4 of pairs pass the cutoff (sphere
// volume (4/3)pi*0.5^3 / box 10^3), so 99.95% of the d/r/mask bytes are
// exactly 0.0f. Two dispatches (same stream -> ordered):
//   1) zerofill kernel: grid-stride float4 zeros over out[4P..14P)
//      (335 MB, ONE contiguous stream — structurally identical to the
//      rocclr poison fill that measures 6.26 TB/s on this chip)
//   2) sparse kernel: writes the pairs index rows (134 MB, 4 contiguous
//      float4 streams, analytic triu inversion, no index loads) and
//      scatter-writes the ~4.4K kept pairs (10 scalars each).
// Written bytes: 335 MB @ fill-rate + 134 MB + eps, vs 470 MB through the
// previous 14-stream path that has twice refused to speed up (R6 float4,
// R8 stream-split both zero-delta).
//
// Numerics: kept pairs use the byte-identical verified R5/R6 computation
// (remainder fixup, no-fma norm, d<=0.5 on rounded d). Non-kept entries
// are +0.0 from the zerofill; reference has -0.0 in the -r_m half, and
// |(-0.0)-(+0.0)| = 0.0 so absmax is unaffected (R5 already passed with
// the opposite zero signs). Fallback kernel (full dense writes, no
// zerofill needed) if P != N(N-1)/2.

#define CUTOFF_F 0.5f
#define BLOCK 256
#define PPT 4
#define ZBLOCKS 2048

__device__ __forceinline__ float pbc_wrap_fast(float r, float L, float h) {
    float t = __fadd_rn(r, h);
    float m = (t >= L) ? __fsub_rn(t, L)
            : (t < 0.0f ? __fadd_rn(t, L) : t);
    return __fsub_rn(m, h);
}

__device__ __forceinline__ void compute_pair_pp(float pix, float piy, float piz,
                                                float pjx, float pjy, float pjz,
                                                float Lx, float Ly, float Lz,
                                                float hx, float hy, float hz,
                                                float& d, float& rx_o,
                                                float& ry_o, float& rz_o,
                                                bool& keep) {
    float rx = __fsub_rn(pix, pjx);
    float ry = __fsub_rn(piy, pjy);
    float rz = __fsub_rn(piz, pjz);

    rx = pbc_wrap_fast(rx, Lx, hx);
    ry = pbc_wrap_fast(ry, Ly, hy);
    rz = pbc_wrap_fast(rz, Lz, hz);

    float d2 = __fadd_rn(__fadd_rn(__fmul_rn(rx, rx), __fmul_rn(ry, ry)),
                         __fmul_rn(rz, rz));
    d = sqrtf(d2);
    keep = (d <= CUTOFF_F);
    rx_o = rx; ry_o = ry; rz_o = rz;
}

__device__ __forceinline__ void write_pair(float* __restrict__ out, long long P,
                                           long long p, float fi, float fj,
                                           float dm, float mx, float my,
                                           float mz, float mk) {
    out[p]          = fi;
    out[P + p]      = fj;
    out[2 * P + p]  = fj;
    out[3 * P + p]  = fi;
    out[4 * P + p]  = dm;
    out[5 * P + p]  = dm;
    long long b0 = 6 * P + 3 * p;
    out[b0 + 0] = mx;  out[b0 + 1] = my;  out[b0 + 2] = mz;
    long long b1 = 6 * P + 3 * (P + p);
    out[b1 + 0] = -mx; out[b1 + 1] = -my; out[b1 + 2] = -mz;
    out[12 * P + p] = mk;
    out[13 * P + p] = mk;
}

// offset of first pair in row i: f(i) = i*(2N-1-i)/2
__device__ __forceinline__ long long row_off(long long i, long long N) {
    return (long long)(((unsigned long long)i *
                        (unsigned long long)(2 * N - 1 - i)) >> 1);
}

// invert triu_indices at p0 -> (i, j)
__device__ __forceinline__ void invert_triu(long long p0, int N,
                                            int& oi, int& oj) {
    const double twoNm1 = (double)(2 * N - 1);
    const double D = twoNm1 * twoNm1 - 8.0 * (double)p0;
    long long i64 = (long long)((twoNm1 - sqrt(D)) * 0.5);
    if (i64 < 0) i64 = 0;
    if (i64 > N - 2) i64 = N - 2;
    while (row_off(i64 + 1, N) <= p0) ++i64;
    while (row_off(i64, N) > p0) --i64;
    oi = (int)i64;
    oj = (int)(p0 - row_off(i64, N) + i64 + 1);
}

// ---------------- dispatch 1: contiguous float4 zero-fill ----------------
__global__ __launch_bounds__(BLOCK)
void nl_zerofill(float* __restrict__ base, long long nfloat) {
    const long long n4 = nfloat >> 2;                    // whole float4s
    const float4 z = make_float4(0.0f, 0.0f, 0.0f, 0.0f);
    const long long stride = (long long)gridDim.x * BLOCK;
    for (long long k = (long long)blockIdx.x * BLOCK + threadIdx.x;
         k < n4; k += stride) {
        reinterpret_cast<float4*>(base)[k] = z;
    }
    // scalar tail (nfloat % 4) — absent for N=4096 but keep it correct
    const long long tail0 = n4 << 2;
    for (long long k = tail0 + (long long)blockIdx.x * BLOCK + threadIdx.x;
         k < nfloat; k += stride) {
        base[k] = 0.0f;
    }
}

// ------------- dispatch 2: pairs rows + scatter of kept pairs ------------
__global__ __launch_bounds__(BLOCK)
void nl_nsq_sparse(const float* __restrict__ pos,
                   const float* __restrict__ box,
                   float*       __restrict__ out,
                   long long P, int N) {
    const long long t  = (long long)blockIdx.x * BLOCK + threadIdx.x;
    const long long p0 = t * PPT;
    if (p0 >= P) return;

    int i, j;
    invert_triu(p0, N, i, j);

    const int nPairs = (int)((P - p0 < (long long)PPT) ? (P - p0)
                                                       : (long long)PPT);
    const bool vec_ok = (nPairs == PPT) && ((P & 3LL) == 0LL);

    const float Lx = box[0], Ly = box[4], Lz = box[8];
    const float hx = Lx * 0.5f, hy = Ly * 0.5f, hz = Lz * 0.5f;

    float pix = pos[3 * i + 0], piy = pos[3 * i + 1], piz = pos[3 * i + 2];

    float fi[PPT], fj[PPT], dv[PPT], rx[PPT], ry[PPT], rz[PPT];
    bool  keep[PPT];

#pragma unroll
    for (int q = 0; q < PPT; ++q) {
        if (q < nPairs) {
            fi[q] = (float)i;
            fj[q] = (float)j;
            float pjx = pos[3 * j + 0];
            float pjy = pos[3 * j + 1];
            float pjz = pos[3 * j + 2];
            compute_pair_pp(pix, piy, piz, pjx, pjy, pjz,
                            Lx, Ly, Lz, hx, hy, hz,
                            dv[q], rx[q], ry[q], rz[q], keep[q]);
            if (q + 1 < nPairs) {
                if (++j >= N) {
                    ++i; j = i + 1;           // row crossing (rare)
                    pix = pos[3 * i + 0];
                    piy = pos[3 * i + 1];
                    piz = pos[3 * i + 2];
                }
            }
        } else {
            fi[q] = fj[q] = dv[q] = rx[q] = ry[q] = rz[q] = 0.0f;
            keep[q] = false;
        }
    }

    // pairs rows: 4 contiguous streams, always dense
    if (vec_ok) {
        float4 vi = make_float4(fi[0], fi[1], fi[2], fi[3]);
        float4 vj = make_float4(fj[0], fj[1], fj[2], fj[3]);
        *reinterpret_cast<float4*>(out + p0)         = vi;
        *reinterpret_cast<float4*>(out + P + p0)     = vj;
        *reinterpret_cast<float4*>(out + 2 * P + p0) = vj;
        *reinterpret_cast<float4*>(out + 3 * P + p0) = vi;
    } else {
        for (int q = 0; q < nPairs; ++q) {
            long long p = p0 + q;
            out[p]         = fi[q];
            out[P + p]     = fj[q];
            out[2 * P + p] = fj[q];
            out[3 * P + p] = fi[q];
        }
    }

    // sparse scatter: only kept pairs (~5e-4 of all pairs) touch d/r/mask
#pragma unroll
    for (int q = 0; q < PPT; ++q) {
        if (q < nPairs && keep[q]) {
            const long long p = p0 + q;
            const float d = dv[q];
            out[4 * P + p] = d;
            out[5 * P + p] = d;
            const long long b0 = 6 * P + 3 * p;
            out[b0 + 0] = rx[q];  out[b0 + 1] = ry[q];  out[b0 + 2] = rz[q];
            const long long b1 = 6 * P + 3 * (P + p);
            out[b1 + 0] = -rx[q]; out[b1 + 1] = -ry[q]; out[b1 + 2] = -rz[q];
            out[12 * P + p] = 1.0f;
            out[13 * P + p] = 1.0f;
        }
    }
}

// ---------------- fallback: dense writes from loaded indices -------------
__global__ __launch_bounds__(BLOCK)
void nl_nsq_loadidx(const float* __restrict__ pos,
                    const float* __restrict__ box,
                    const int*   __restrict__ ip,
                    const int*   __restrict__ jp,
                    float*       __restrict__ out,
                    long long P) {
    const long long p = (long long)blockIdx.x * BLOCK + threadIdx.x;
    if (p >= P) return;

    const int i = ip[p];
    const int j = jp[p];

    const float Lx = box[0], Ly = box[4], Lz = box[8];
    const float hx = Lx * 0.5f, hy = Ly * 0.5f, hz = Lz * 0.5f;

    float d, rx, ry, rz;
    bool keep;
    compute_pair_pp(pos[3 * i + 0], pos[3 * i + 1], pos[3 * i + 2],
                    pos[3 * j + 0], pos[3 * j + 1], pos[3 * j + 2],
                    Lx, Ly, Lz, hx, hy, hz, d, rx, ry, rz, keep);
    const float dm = keep ? d  : 0.0f;
    const float mx = keep ? rx : 0.0f;
    const float my = keep ? ry : 0.0f;
    const float mz = keep ? rz : 0.0f;
    const float mk = keep ? 1.0f : 0.0f;
    write_pair(out, P, p, (float)i, (float)j, dm, mx, my, mz, mk);
}

extern "C" void kernel_launch(void* const* d_in, const int* in_sizes, int n_in,
                              void* d_out, int out_size, void* d_ws, size_t ws_size,
                              hipStream_t stream) {
    const float* pos = (const float*)d_in[0];  // [N,3]
    const float* box = (const float*)d_in[1];  // [3,3]
    const int*   ip  = (const int*)d_in[2];    // [P]
    const int*   jp  = (const int*)d_in[3];    // [P]
    float*       out = (float*)d_out;

    const long long P = (long long)in_sizes[2];
    const int       N = in_sizes[0] / 3;

    if (P == (long long)N * (N - 1) / 2) {
        // 1) zero d_full + r_full + mask regions: out[4P .. 14P)
        nl_zerofill<<<ZBLOCKS, BLOCK, 0, stream>>>(out + 4 * P, 10 * P);
        // 2) pairs rows + kept-pair scatter (ordered after zerofill: same
        //    stream)
        const long long threads = (P + PPT - 1) / PPT;
        const long long grid    = (threads + BLOCK - 1) / BLOCK;
        nl_nsq_sparse<<<(dim3)(unsigned)grid, BLOCK, 0, stream>>>(
            pos, box, out, P, N);
    } else {
        const long long grid = (P + BLOCK - 1) / BLOCK;
        nl_nsq_loadidx<<<(dim3)(unsigned)grid, BLOCK, 0, stream>>>(
            pos, box, ip, jp, out, P);
    }
}